// Round 11
// baseline (342.797 us; speedup 1.0000x reference)
//
#include <hip/hip_runtime.h>
#include <hip/hip_fp16.h>

#define N_NODES 100000
#define N_EDGES 1600000
#define DIM 64
#define NEG_SLOPE 0.01f

#define BNODES 128            // nodes per bucket
#define NBUCK 782             // ceil(100000/128)
#define BCAP 4096             // slab capacity per bucket (avg fill ~2046)
#define BLOCKS1 256           // scatter blocks (1 per CU)
#define THREADS1 1024         // 16 waves/CU
#define EPB (N_EDGES / BLOCKS1)   // 6250 exactly

typedef _Float16 half8 __attribute__((ext_vector_type(8)));
typedef float float4v __attribute__((ext_vector_type(4)));

// ---- weight prep: W fp32 [k][f] -> WT16 fp16 transposed [f][k], 4 layers ----
__global__ void prep_weights(const float* __restrict__ W0, const float* __restrict__ W1,
                             const float* __restrict__ W2, const float* __restrict__ W3,
                             __half* __restrict__ WT16) {
    const float* Ws[4] = {W0, W1, W2, W3};
    const float* W = Ws[blockIdx.x];
    __half* dst = WT16 + (size_t)blockIdx.x * DIM * DIM;
    for (int e = threadIdx.x; e < DIM * DIM; e += 256) {
        int k = e >> 6, f = e & 63;
        dst[f * DIM + k] = __float2half(W[e]);
    }
}

// ---- pass 1: LDS counting-sort scatter ----
__global__ __launch_bounds__(THREADS1) void bucket_scatter(const int* __restrict__ src,
                                                           const int* __restrict__ dst,
                                                           int* __restrict__ gcur,   // stride 16 (64B pad)
                                                           int* __restrict__ bdata) {
    __shared__ int cnt[NBUCK];
    __shared__ int cur[NBUCK];
    __shared__ int lexcl[NBUCK];
    __shared__ int base[NBUCK];
    __shared__ int scan[THREADS1];
    __shared__ int sorted_e[EPB];
    __shared__ unsigned short sorted_b[EPB];

    const int tid = threadIdx.x;
    for (int i = tid; i < NBUCK; i += THREADS1) { cnt[i] = 0; cur[i] = 0; }
    __syncthreads();

    const int e0 = blockIdx.x * EPB;
    const int e1 = e0 + EPB;

    for (int e = e0 + tid; e < e1; e += THREADS1)
        atomicAdd(&cnt[dst[e] >> 7], 1);
    __syncthreads();

    int v = (tid < NBUCK) ? cnt[tid] : 0;
    scan[tid] = v;
    __syncthreads();
    for (int s = 1; s < THREADS1; s <<= 1) {
        int a = (tid >= s) ? scan[tid - s] : 0;
        __syncthreads();
        scan[tid] += a;
        __syncthreads();
    }
    if (tid < NBUCK) lexcl[tid] = scan[tid] - v;

    if (tid < NBUCK) {
        int c = cnt[tid];
        base[tid] = c ? atomicAdd(&gcur[tid * 16], c) : 0;
    }
    __syncthreads();

    for (int e = e0 + tid; e < e1; e += THREADS1) {
        int d = dst[e];
        int b = d >> 7;
        int p = lexcl[b] + atomicAdd(&cur[b], 1);
        sorted_e[p] = src[e] | ((d & 127) << 17);
        sorted_b[p] = (unsigned short)b;
    }
    __syncthreads();

    for (int i = tid; i < EPB; i += THREADS1) {
        int b = sorted_b[i];
        bdata[(size_t)b * BCAP + base[b] + (i - lexcl[b])] = sorted_e[i];
    }
}

// ---- exclusive scan of bucket sizes -> bucket csr base ----
__global__ void bucket_scan(const int* __restrict__ gcur, int* __restrict__ bbase) {
    __shared__ int sm[1024];
    const int tid = threadIdx.x;
    int v = (tid < NBUCK) ? gcur[tid * 16] : 0;
    sm[tid] = v;
    __syncthreads();
    for (int s = 1; s < 1024; s <<= 1) {
        int a = ((int)tid >= s) ? sm[tid - s] : 0;
        __syncthreads();
        sm[tid] += a;
        __syncthreads();
    }
    if (tid < NBUCK) bbase[tid] = sm[tid] - v;   // exclusive
}

// ---- pass 2: per-bucket counting sort -> offsets, dinv, csr (single-writer) ----
__global__ __launch_bounds__(256) void bucket_build(const int* __restrict__ bdata,
                                                    const int* __restrict__ gcur,
                                                    const int* __restrict__ bbase,
                                                    int* __restrict__ offsets,
                                                    float* __restrict__ dinv,
                                                    int* __restrict__ csr) {
    __shared__ int cnt[BNODES];
    __shared__ int excl[BNODES];
    const int tid = threadIdx.x;
    const int b = blockIdx.x;
    const int sz = gcur[b * 16];
    const int* bd = bdata + (size_t)b * BCAP;
    const int cbase = bbase[b];

    for (int i = tid; i < BNODES; i += 256) cnt[i] = 0;
    __syncthreads();
    for (int i = tid; i < sz; i += 256)
        atomicAdd(&cnt[bd[i] >> 17], 1);
    __syncthreads();
    if (tid == 0) {
        int run = 0;
        for (int j = 0; j < BNODES; ++j) { excl[j] = run; run += cnt[j]; }
    }
    __syncthreads();

    const int nb = b * BNODES;
    for (int i = tid; i < BNODES; i += 256) {
        int n = nb + i;
        if (n < N_NODES) {
            offsets[n] = cbase + excl[i];
            dinv[n] = rsqrtf((float)(cnt[i] + 1));   // deg incl self-loop
        }
    }
    if (b == NBUCK - 1 && tid == 0) offsets[N_NODES] = N_EDGES;

    for (int i = tid; i < BNODES; i += 256) cnt[i] = 0;   // reuse as cursor
    __syncthreads();
    for (int i = tid; i < sz; i += 256) {
        int v = bd[i];
        int l = v >> 17;
        int pos = cbase + excl[l] + atomicAdd(&cnt[l], 1);
        csr[pos] = (v & 0x1FFFF) << 6;   // element offset src*DIM
    }
}

// ---- staging helpers ----
__device__ __forceinline__ void stage8(__half* dst, const float* __restrict__ X, size_t off) {
    float4 f0 = *(const float4*)(X + off);
    float4 f1 = *(const float4*)(X + off + 4);
    __half2 h0 = __floats2half2_rn(f0.x, f0.y);
    __half2 h1 = __floats2half2_rn(f0.z, f0.w);
    __half2 h2 = __floats2half2_rn(f1.x, f1.y);
    __half2 h3 = __floats2half2_rn(f1.z, f1.w);
    uint4 u;
    u.x = *(unsigned int*)&h0; u.y = *(unsigned int*)&h1;
    u.z = *(unsigned int*)&h2; u.w = *(unsigned int*)&h3;
    *(uint4*)dst = u;
}
__device__ __forceinline__ void stage8(__half* dst, const __half* __restrict__ X, size_t off) {
    *(uint4*)dst = *(const uint4*)(X + off);
}

// ---- MFMA fp16 matmul + dinv (layer 1 only): G16[r,f] = dinv[r]*(X[r,:]@W) ----
#define XPAD 72
__global__ __launch_bounds__(256) void mm_kernel(const float* __restrict__ X,
                                                 const __half* __restrict__ WT,  // [f][k] fp16
                                                 const float* __restrict__ dinv,
                                                 __half* __restrict__ G16) {
    __shared__ __align__(16) __half xs[64][XPAD];
    __shared__ __align__(16) __half ws[64][XPAD];
    const int t = threadIdx.x;
    const int rbase = blockIdx.x * 64;

    for (int c = t; c < 512; c += 256) {
        int row = c >> 3, koff = (c & 7) * 8;
        int grow = rbase + row;
        if (grow < N_NODES) {
            stage8(&xs[row][koff], X, (size_t)grow * DIM + koff);
        } else {
            *(uint4*)&xs[row][koff] = make_uint4(0, 0, 0, 0);
        }
        stage8(&ws[row][koff], WT, (size_t)row * DIM + koff);
    }
    __syncthreads();

    const int wave = t >> 6;
    const int lane = t & 63;
    const int q = lane >> 4;
    const int c16 = lane & 15;
    const int n0 = wave * 16;

    half8 b0 = *(const half8*)&xs[n0 + c16][q * 8];
    half8 b1 = *(const half8*)&xs[n0 + c16][32 + q * 8];

    const int gnode = rbase + n0 + c16;
    float di = (gnode < N_NODES) ? dinv[gnode] : 0.f;

#pragma unroll
    for (int ft = 0; ft < 4; ++ft) {
        const int f0 = ft * 16;
        half8 a0 = *(const half8*)&ws[f0 + c16][q * 8];
        half8 a1 = *(const half8*)&ws[f0 + c16][32 + q * 8];
        float4v acc = {0.f, 0.f, 0.f, 0.f};
        acc = __builtin_amdgcn_mfma_f32_16x16x32_f16(a0, b0, acc, 0, 0, 0);
        acc = __builtin_amdgcn_mfma_f32_16x16x32_f16(a1, b1, acc, 0, 0, 0);
        if (gnode < N_NODES) {
            __half2 p0 = __floats2half2_rn(di * acc[0], di * acc[1]);
            __half2 p1 = __floats2half2_rn(di * acc[2], di * acc[3]);
            uint2 u;
            u.x = *(unsigned int*)&p0;
            u.y = *(unsigned int*)&p1;
            *(uint2*)(G16 + (size_t)gnode * DIM + f0 + q * 4) = u;
        }
    }
}

// ---- fused aggregate + next-layer matmul ----
// Wave owns a 16-node tile. Per node: gather fp16 rows (8 slots x 16B chunks,
// 2-deep unroll), butterfly-reduce, bias+leakyrelu -> act row (fp16) to a
// per-wave LDS tile. After 16 nodes: G_next[tile] = dinv * (act @ W) via
// 8x mfma_f32_16x16x32_f16 (same math as mm_kernel; W tile block-staged in LDS).
// FINAL=true: no mm phase, write fp32 d_out instead of LDS act.
template <bool FINAL>
__global__ __launch_bounds__(256) void aggmm_kernel(const __half* __restrict__ Gin,
                                                    const int* __restrict__ csr,
                                                    const int* __restrict__ offsets,
                                                    const float* __restrict__ dinv,
                                                    const float* __restrict__ bias,
                                                    const __half* __restrict__ WT,  // next layer [f][k]
                                                    void* __restrict__ outp) {
    __shared__ __align__(16) __half ws[64][XPAD];       // next-layer W^T tile
    __shared__ __align__(16) __half act[4][16][XPAD];   // per-wave act tiles
    const int t = threadIdx.x;
    const int wave = t >> 6;
    const int lane = t & 63;

    if (!FINAL) {
        for (int c = t; c < 512; c += 256)
            stage8(&ws[c >> 3][(c & 7) * 8], WT, (size_t)(c >> 3) * DIM + (c & 7) * 8);
        __syncthreads();
    }

    const int slot = lane >> 3;          // 0..7
    const int sub  = lane & 7;
    const int fc   = sub * 8;
    const int tileBase = blockIdx.x * 64 + wave * 16;

    for (int i = 0; i < 16; ++i) {
        const int wid = tileBase + i;
        if (wid >= N_NODES) break;
        const int beg = offsets[wid], end = offsets[wid + 1];

        __half2 h0 = __float2half2_rn(0.f), h1 = h0, h2 = h0, h3 = h0;

#define PKACC(vraw)                                     \
        {                                               \
            const __half2* hp = (const __half2*)&(vraw);\
            h0 = __hadd2(h0, hp[0]);                    \
            h1 = __hadd2(h1, hp[1]);                    \
            h2 = __hadd2(h2, hp[2]);                    \
            h3 = __hadd2(h3, hp[3]);                    \
        }
        int e = beg + slot;
        for (; e + 8 < end; e += 16) {
            int p0 = csr[e];
            int p1 = csr[e + 8];
            float4 v0 = *(const float4*)(Gin + (size_t)p0 + fc);
            float4 v1 = *(const float4*)(Gin + (size_t)p1 + fc);
            PKACC(v0)
            PKACC(v1)
        }
        if (e < end) {
            int p0 = csr[e];
            float4 v0 = *(const float4*)(Gin + (size_t)p0 + fc);
            PKACC(v0)
        }
#undef PKACC

        float acc[8];
        {
            float2 f;
            f = __half22float2(h0); acc[0] = f.x; acc[1] = f.y;
            f = __half22float2(h1); acc[2] = f.x; acc[3] = f.y;
            f = __half22float2(h2); acc[4] = f.x; acc[5] = f.y;
            f = __half22float2(h3); acc[6] = f.x; acc[7] = f.y;
        }
#pragma unroll
        for (int k = 0; k < 8; ++k) {
            acc[k] += __shfl_xor(acc[k], 8, 64);
            acc[k] += __shfl_xor(acc[k], 16, 64);
            acc[k] += __shfl_xor(acc[k], 32, 64);
        }

        if (slot == 0) {   // lanes 0..7 hold features fc..fc+7
            // self-loop row, exactly once, post-reduction
            float4 vs = *(const float4*)(Gin + (size_t)wid * DIM + fc);
            {
                const __half2* hp = (const __half2*)&vs;
                float2 f0 = __half22float2(hp[0]);
                float2 f1 = __half22float2(hp[1]);
                float2 f2 = __half22float2(hp[2]);
                float2 f3 = __half22float2(hp[3]);
                acc[0] += f0.x; acc[1] += f0.y;
                acc[2] += f1.x; acc[3] += f1.y;
                acc[4] += f2.x; acc[5] += f2.y;
                acc[6] += f3.x; acc[7] += f3.y;
            }
            float di = dinv[wid];
            float4 b0 = *(const float4*)(bias + fc);
            float4 b1 = *(const float4*)(bias + fc + 4);
            float r[8];
            r[0] = di * acc[0] + b0.x;
            r[1] = di * acc[1] + b0.y;
            r[2] = di * acc[2] + b0.z;
            r[3] = di * acc[3] + b0.w;
            r[4] = di * acc[4] + b1.x;
            r[5] = di * acc[5] + b1.y;
            r[6] = di * acc[6] + b1.z;
            r[7] = di * acc[7] + b1.w;
#pragma unroll
            for (int k = 0; k < 8; ++k)
                r[k] = (r[k] >= 0.f) ? r[k] : NEG_SLOPE * r[k];

            if (FINAL) {
                float* out = (float*)outp;
                *(float4*)(out + (size_t)wid * DIM + fc)     = make_float4(r[0], r[1], r[2], r[3]);
                *(float4*)(out + (size_t)wid * DIM + fc + 4) = make_float4(r[4], r[5], r[6], r[7]);
            } else {
                __half2 q0 = __floats2half2_rn(r[0], r[1]);
                __half2 q1 = __floats2half2_rn(r[2], r[3]);
                __half2 q2 = __floats2half2_rn(r[4], r[5]);
                __half2 q3 = __floats2half2_rn(r[6], r[7]);
                uint4 u;
                u.x = *(unsigned int*)&q0;
                u.y = *(unsigned int*)&q1;
                u.z = *(unsigned int*)&q2;
                u.w = *(unsigned int*)&q3;
                *(uint4*)&act[wave][i][fc] = u;
            }
        }
    }

    if (FINAL) return;

    // ---- mm phase (per-wave; same wave wrote its act tile -> no barrier) ----
    const int q = lane >> 4;
    const int c16 = lane & 15;
    half8 b0 = *(const half8*)&act[wave][c16][q * 8];
    half8 b1 = *(const half8*)&act[wave][c16][32 + q * 8];

    const int gnode = tileBase + c16;
    float di = (gnode < N_NODES) ? dinv[gnode] : 0.f;
    __half* Gout = (__half*)outp;

#pragma unroll
    for (int ft = 0; ft < 4; ++ft) {
        const int f0 = ft * 16;
        half8 a0 = *(const half8*)&ws[f0 + c16][q * 8];
        half8 a1 = *(const half8*)&ws[f0 + c16][32 + q * 8];
        float4v acc = {0.f, 0.f, 0.f, 0.f};
        acc = __builtin_amdgcn_mfma_f32_16x16x32_f16(a0, b0, acc, 0, 0, 0);
        acc = __builtin_amdgcn_mfma_f32_16x16x32_f16(a1, b1, acc, 0, 0, 0);
        if (gnode < N_NODES) {
            __half2 p0 = __floats2half2_rn(di * acc[0], di * acc[1]);
            __half2 p1 = __floats2half2_rn(di * acc[2], di * acc[3]);
            uint2 u;
            u.x = *(unsigned int*)&p0;
            u.y = *(unsigned int*)&p1;
            *(uint2*)(Gout + (size_t)gnode * DIM + f0 + q * 4) = u;
        }
    }
}

extern "C" void kernel_launch(void* const* d_in, const int* in_sizes, int n_in,
                              void* d_out, int out_size, void* d_ws, size_t ws_size,
                              hipStream_t stream) {
    const float* x = (const float*)d_in[0];
    const int* ei = (const int*)d_in[1];
    const int* src = ei;
    const int* dst = ei + N_EDGES;
    const float* W[4] = {(const float*)d_in[2], (const float*)d_in[4],
                         (const float*)d_in[6], (const float*)d_in[8]};
    const float* b[4] = {(const float*)d_in[3], (const float*)d_in[5],
                         (const float*)d_in[7], (const float*)d_in[9]};
    float* out = (float*)d_out;

    char* ws = (char*)d_ws;
    size_t off = 0;
    auto alloc = [&](size_t bytes) -> void* {
        void* p = ws + off;
        off = (off + bytes + 255) & ~(size_t)255;
        return p;
    };
    __half* GA    = (__half*)alloc((size_t)N_NODES * DIM * sizeof(__half));   // 12.8 MB
    __half* GB    = (__half*)alloc((size_t)N_NODES * DIM * sizeof(__half));   // 12.8 MB
    __half* WT16  = (__half*)alloc((size_t)4 * DIM * DIM * sizeof(__half));   // 32 KB
    int*   csr    = (int*)alloc((size_t)N_EDGES * sizeof(int));               // 6.4 MB
    int*   bdata  = (int*)alloc((size_t)NBUCK * BCAP * sizeof(int));          // 12.8 MB
    int*   gcur   = (int*)alloc((size_t)NBUCK * 16 * sizeof(int));            // 50 KB
    int*   bbase  = (int*)alloc((size_t)(NBUCK + 1) * sizeof(int));
    int*   offsets= (int*)alloc((size_t)(N_NODES + 1) * sizeof(int));
    float* dinv   = (float*)alloc((size_t)N_NODES * sizeof(float));

    hipMemsetAsync(gcur, 0, (size_t)NBUCK * 16 * sizeof(int), stream);
    prep_weights<<<4, 256, 0, stream>>>(W[0], W[1], W[2], W[3], WT16);

    bucket_scatter<<<BLOCKS1, THREADS1, 0, stream>>>(src, dst, gcur, bdata);
    bucket_scan<<<1, 1024, 0, stream>>>(gcur, bbase);
    bucket_build<<<NBUCK, 256, 0, stream>>>(bdata, gcur, bbase, offsets, dinv, csr);

    const int MM_GRID = (N_NODES + 63) / 64;          // 1563

    // L1 matmul: x (fp32) @ W1 -> GA
    mm_kernel<<<MM_GRID, 256, 0, stream>>>(x, WT16, dinv, GA);
    // L1 agg + L2 matmul fused -> GB
    aggmm_kernel<false><<<MM_GRID, 256, 0, stream>>>(GA, csr, offsets, dinv, b[0],
                                                     WT16 + DIM * DIM, GB);
    // L2 agg + L3 matmul -> GA
    aggmm_kernel<false><<<MM_GRID, 256, 0, stream>>>(GB, csr, offsets, dinv, b[1],
                                                     WT16 + 2 * DIM * DIM, GA);
    // L3 agg + L4 matmul -> GB
    aggmm_kernel<false><<<MM_GRID, 256, 0, stream>>>(GA, csr, offsets, dinv, b[2],
                                                     WT16 + 3 * DIM * DIM, GB);
    // L4 agg -> fp32 out
    aggmm_kernel<true><<<MM_GRID, 256, 0, stream>>>(GB, csr, offsets, dinv, b[3],
                                                    nullptr, out);
}

// Round 12
// 308.018 us; speedup vs baseline: 1.1129x; 1.1129x over previous
//
#include <hip/hip_runtime.h>
#include <hip/hip_fp16.h>

#define N_NODES 100000
#define N_EDGES 1600000
#define DIM 64
#define NEG_SLOPE 0.01f

#define BNODES 128            // nodes per bucket
#define NBUCK 782             // ceil(100000/128)
#define BCAP 4096             // slab capacity per bucket (avg fill ~2046)
#define BLOCKS1 256           // scatter blocks (1 per CU)
#define THREADS1 1024         // 16 waves/CU
#define EPB (N_EDGES / BLOCKS1)   // 6250 exactly

typedef _Float16 half8 __attribute__((ext_vector_type(8)));
typedef float float4v __attribute__((ext_vector_type(4)));

// ---- weight prep: W fp32 [k][f] -> WT16 fp16 transposed [f][k], 4 layers ----
__global__ void prep_weights(const float* __restrict__ W0, const float* __restrict__ W1,
                             const float* __restrict__ W2, const float* __restrict__ W3,
                             __half* __restrict__ WT16) {
    const float* Ws[4] = {W0, W1, W2, W3};
    const float* W = Ws[blockIdx.x];
    __half* dst = WT16 + (size_t)blockIdx.x * DIM * DIM;
    for (int e = threadIdx.x; e < DIM * DIM; e += 256) {
        int k = e >> 6, f = e & 63;
        dst[f * DIM + k] = __float2half(W[e]);
    }
}

// ---- pass 1: LDS counting-sort scatter ----
__global__ __launch_bounds__(THREADS1) void bucket_scatter(const int* __restrict__ src,
                                                           const int* __restrict__ dst,
                                                           int* __restrict__ gcur,   // stride 16 (64B pad)
                                                           int* __restrict__ bdata) {
    __shared__ int cnt[NBUCK];
    __shared__ int cur[NBUCK];
    __shared__ int lexcl[NBUCK];
    __shared__ int base[NBUCK];
    __shared__ int scan[THREADS1];
    __shared__ int sorted_e[EPB];
    __shared__ unsigned short sorted_b[EPB];

    const int tid = threadIdx.x;
    for (int i = tid; i < NBUCK; i += THREADS1) { cnt[i] = 0; cur[i] = 0; }
    __syncthreads();

    const int e0 = blockIdx.x * EPB;
    const int e1 = e0 + EPB;

    for (int e = e0 + tid; e < e1; e += THREADS1)
        atomicAdd(&cnt[dst[e] >> 7], 1);
    __syncthreads();

    int v = (tid < NBUCK) ? cnt[tid] : 0;
    scan[tid] = v;
    __syncthreads();
    for (int s = 1; s < THREADS1; s <<= 1) {
        int a = (tid >= s) ? scan[tid - s] : 0;
        __syncthreads();
        scan[tid] += a;
        __syncthreads();
    }
    if (tid < NBUCK) lexcl[tid] = scan[tid] - v;

    if (tid < NBUCK) {
        int c = cnt[tid];
        base[tid] = c ? atomicAdd(&gcur[tid * 16], c) : 0;
    }
    __syncthreads();

    for (int e = e0 + tid; e < e1; e += THREADS1) {
        int d = dst[e];
        int b = d >> 7;
        int p = lexcl[b] + atomicAdd(&cur[b], 1);
        sorted_e[p] = src[e] | ((d & 127) << 17);
        sorted_b[p] = (unsigned short)b;
    }
    __syncthreads();

    for (int i = tid; i < EPB; i += THREADS1) {
        int b = sorted_b[i];
        bdata[(size_t)b * BCAP + base[b] + (i - lexcl[b])] = sorted_e[i];
    }
}

// ---- pass 2: per-bucket counting sort -> offsets, dinv, csr (single-writer) ----
// Computes its own csr base (prefix of gcur over buckets < b) — no scan kernel.
// csr entries are pre-shifted element offsets (src * DIM).
__global__ __launch_bounds__(256) void bucket_build(const int* __restrict__ bdata,
                                                    const int* __restrict__ gcur,
                                                    int* __restrict__ offsets,
                                                    float* __restrict__ dinv,
                                                    int* __restrict__ csr) {
    __shared__ int cnt[BNODES];
    __shared__ int excl[BNODES];
    __shared__ int part[256];
    const int tid = threadIdx.x;
    const int b = blockIdx.x;
    const int sz = gcur[b * 16];
    const int* bd = bdata + (size_t)b * BCAP;

    // cbase = sum of bucket sizes for buckets < b (parallel reduce, L2-hot)
    int s = 0;
    for (int i = tid; i < b; i += 256) s += gcur[i * 16];
    part[tid] = s;
    __syncthreads();
    for (int st = 128; st > 0; st >>= 1) {
        if (tid < st) part[tid] += part[tid + st];
        __syncthreads();
    }
    const int cbase = part[0];
    __syncthreads();

    for (int i = tid; i < BNODES; i += 256) cnt[i] = 0;
    __syncthreads();
    for (int i = tid; i < sz; i += 256)
        atomicAdd(&cnt[bd[i] >> 17], 1);
    __syncthreads();
    if (tid == 0) {
        int run = 0;
        for (int j = 0; j < BNODES; ++j) { excl[j] = run; run += cnt[j]; }
    }
    __syncthreads();

    const int nb = b * BNODES;
    for (int i = tid; i < BNODES; i += 256) {
        int n = nb + i;
        if (n < N_NODES) {
            offsets[n] = cbase + excl[i];
            dinv[n] = rsqrtf((float)(cnt[i] + 1));   // deg incl self-loop
        }
    }
    if (b == NBUCK - 1 && tid == 0) offsets[N_NODES] = N_EDGES;

    for (int i = tid; i < BNODES; i += 256) cnt[i] = 0;   // reuse as cursor
    __syncthreads();
    for (int i = tid; i < sz; i += 256) {
        int v = bd[i];
        int l = v >> 17;
        int pos = cbase + excl[l] + atomicAdd(&cnt[l], 1);
        csr[pos] = (v & 0x1FFFF) << 6;   // element offset src*DIM
    }
}

// ---- staging helpers ----
__device__ __forceinline__ void stage8(__half* dst, const float* __restrict__ X, size_t off) {
    float4 f0 = *(const float4*)(X + off);
    float4 f1 = *(const float4*)(X + off + 4);
    __half2 h0 = __floats2half2_rn(f0.x, f0.y);
    __half2 h1 = __floats2half2_rn(f0.z, f0.w);
    __half2 h2 = __floats2half2_rn(f1.x, f1.y);
    __half2 h3 = __floats2half2_rn(f1.z, f1.w);
    uint4 u;
    u.x = *(unsigned int*)&h0; u.y = *(unsigned int*)&h1;
    u.z = *(unsigned int*)&h2; u.w = *(unsigned int*)&h3;
    *(uint4*)dst = u;
}
__device__ __forceinline__ void stage8(__half* dst, const __half* __restrict__ X, size_t off) {
    *(uint4*)dst = *(const uint4*)(X + off);
}

// ---- MFMA fp16 matmul + dinv: G16[r,f] = (half) dinv[r] * sum_k X[r,k] W[k,f] ----
#define XPAD 72
template <typename TIN>
__global__ __launch_bounds__(256) void mm_kernel(const TIN* __restrict__ X,
                                                 const __half* __restrict__ WT,  // [f][k] fp16
                                                 const float* __restrict__ dinv,
                                                 __half* __restrict__ G16) {
    __shared__ __align__(16) __half xs[64][XPAD];
    __shared__ __align__(16) __half ws[64][XPAD];
    const int t = threadIdx.x;
    const int rbase = blockIdx.x * 64;

    for (int c = t; c < 512; c += 256) {
        int row = c >> 3, koff = (c & 7) * 8;
        int grow = rbase + row;
        if (grow < N_NODES) {
            stage8(&xs[row][koff], X, (size_t)grow * DIM + koff);
        } else {
            *(uint4*)&xs[row][koff] = make_uint4(0, 0, 0, 0);
        }
        stage8(&ws[row][koff], WT, (size_t)row * DIM + koff);
    }
    __syncthreads();

    const int wave = t >> 6;
    const int lane = t & 63;
    const int q = lane >> 4;
    const int c16 = lane & 15;
    const int n0 = wave * 16;

    half8 b0 = *(const half8*)&xs[n0 + c16][q * 8];
    half8 b1 = *(const half8*)&xs[n0 + c16][32 + q * 8];

    const int gnode = rbase + n0 + c16;
    float di = (gnode < N_NODES) ? dinv[gnode] : 0.f;

#pragma unroll
    for (int ft = 0; ft < 4; ++ft) {
        const int f0 = ft * 16;
        half8 a0 = *(const half8*)&ws[f0 + c16][q * 8];
        half8 a1 = *(const half8*)&ws[f0 + c16][32 + q * 8];
        float4v acc = {0.f, 0.f, 0.f, 0.f};
        acc = __builtin_amdgcn_mfma_f32_16x16x32_f16(a0, b0, acc, 0, 0, 0);
        acc = __builtin_amdgcn_mfma_f32_16x16x32_f16(a1, b1, acc, 0, 0, 0);
        if (gnode < N_NODES) {
            __half2 p0 = __floats2half2_rn(di * acc[0], di * acc[1]);
            __half2 p1 = __floats2half2_rn(di * acc[2], di * acc[3]);
            uint2 u;
            u.x = *(unsigned int*)&p0;
            u.y = *(unsigned int*)&p1;
            *(uint2*)(G16 + (size_t)gnode * DIM + f0 + q * 4) = u;
        }
    }
}

// ---------------- aggregate: persistent waves, 2 nodes per wave ----------------
// Lane layout: grp = lane>>5 picks the node of the pair; within each 32-lane
// group: 4 slots x 8 lanes, each lane owns a 16B row chunk. One load
// instruction still fetches 8 rows (4 per node) but the per-node epilogue cost
// halves (2 shfl levels, one epilogue pass serves both nodes) and the per-wave
// serial node-loop has half the iterations.
#define AGG_BLOCKS 2048
#define AGG_WAVES (AGG_BLOCKS * 4)
#define NPAIRS (N_NODES / 2)
template <bool FINAL>
__global__ __launch_bounds__(256) void agg_kernel(const __half* __restrict__ G16,
                                                  const int* __restrict__ csr,
                                                  const int* __restrict__ offsets,
                                                  const float* __restrict__ dinv,
                                                  const float* __restrict__ bias,
                                                  void* __restrict__ outp) {
    const int gw = (blockIdx.x * 256 + threadIdx.x) >> 6;   // global wave id
    const int lane = threadIdx.x & 63;
    const int grp  = lane >> 5;          // node of the pair
    const int slot = (lane >> 3) & 3;    // 0..3
    const int sub  = lane & 7;           // 16B chunk within row
    const int fc   = sub * 8;

    for (int p = gw; p < NPAIRS; p += AGG_WAVES) {
        const int wid = p * 2 + grp;
        const int beg = offsets[wid], end = offsets[wid + 1];

        __half2 h0 = __float2half2_rn(0.f), h1 = h0, h2 = h0, h3 = h0;

#define PKACC(vraw)                                     \
        {                                               \
            const __half2* hp = (const __half2*)&(vraw);\
            h0 = __hadd2(h0, hp[0]);                    \
            h1 = __hadd2(h1, hp[1]);                    \
            h2 = __hadd2(h2, hp[2]);                    \
            h3 = __hadd2(h3, hp[3]);                    \
        }

        int e = beg + slot;
        for (; e + 4 < end; e += 8) {
            int p0 = csr[e];
            int p1 = csr[e + 4];
            float4 v0 = *(const float4*)(G16 + (size_t)p0 + fc);
            float4 v1 = *(const float4*)(G16 + (size_t)p1 + fc);
            PKACC(v0)
            PKACC(v1)
        }
        if (e < end) {
            int p0 = csr[e];
            float4 v0 = *(const float4*)(G16 + (size_t)p0 + fc);
            PKACC(v0)
        }
#undef PKACC

        float acc[8];
        {
            float2 f;
            f = __half22float2(h0); acc[0] = f.x; acc[1] = f.y;
            f = __half22float2(h1); acc[2] = f.x; acc[3] = f.y;
            f = __half22float2(h2); acc[4] = f.x; acc[5] = f.y;
            f = __half22float2(h3); acc[6] = f.x; acc[7] = f.y;
        }
        // reduce 4 slots within each 32-lane group (lane bits 3,4)
#pragma unroll
        for (int k = 0; k < 8; ++k) {
            acc[k] += __shfl_xor(acc[k], 8, 64);
            acc[k] += __shfl_xor(acc[k], 16, 64);
        }

        if (slot == 0) {   // lanes 0-7 (node A) and 32-39 (node B)
            // self-loop row: exactly once, post-reduction
            float4 vs = *(const float4*)(G16 + (size_t)wid * DIM + fc);
            {
                const __half2* hp = (const __half2*)&vs;
                float2 f0 = __half22float2(hp[0]);
                float2 f1 = __half22float2(hp[1]);
                float2 f2 = __half22float2(hp[2]);
                float2 f3 = __half22float2(hp[3]);
                acc[0] += f0.x; acc[1] += f0.y;
                acc[2] += f1.x; acc[3] += f1.y;
                acc[4] += f2.x; acc[5] += f2.y;
                acc[6] += f3.x; acc[7] += f3.y;
            }

            float di = dinv[wid];
            float4 b0 = *(const float4*)(bias + fc);
            float4 b1 = *(const float4*)(bias + fc + 4);
            float r[8];
            r[0] = di * acc[0] + b0.x;
            r[1] = di * acc[1] + b0.y;
            r[2] = di * acc[2] + b0.z;
            r[3] = di * acc[3] + b0.w;
            r[4] = di * acc[4] + b1.x;
            r[5] = di * acc[5] + b1.y;
            r[6] = di * acc[6] + b1.z;
            r[7] = di * acc[7] + b1.w;
#pragma unroll
            for (int k = 0; k < 8; ++k)
                r[k] = (r[k] >= 0.f) ? r[k] : NEG_SLOPE * r[k];

            if (FINAL) {
                float* out = (float*)outp;
                *(float4*)(out + (size_t)wid * DIM + fc)     = make_float4(r[0], r[1], r[2], r[3]);
                *(float4*)(out + (size_t)wid * DIM + fc + 4) = make_float4(r[4], r[5], r[6], r[7]);
            } else {
                __half* act = (__half*)outp;
                __half2 q0 = __floats2half2_rn(r[0], r[1]);
                __half2 q1 = __floats2half2_rn(r[2], r[3]);
                __half2 q2 = __floats2half2_rn(r[4], r[5]);
                __half2 q3 = __floats2half2_rn(r[6], r[7]);
                uint4 u;
                u.x = *(unsigned int*)&q0;
                u.y = *(unsigned int*)&q1;
                u.z = *(unsigned int*)&q2;
                u.w = *(unsigned int*)&q3;
                *(uint4*)(act + (size_t)wid * DIM + fc) = u;
            }
        }
    }
}

extern "C" void kernel_launch(void* const* d_in, const int* in_sizes, int n_in,
                              void* d_out, int out_size, void* d_ws, size_t ws_size,
                              hipStream_t stream) {
    const float* x = (const float*)d_in[0];
    const int* ei = (const int*)d_in[1];
    const int* src = ei;
    const int* dst = ei + N_EDGES;
    const float* W[4] = {(const float*)d_in[2], (const float*)d_in[4],
                         (const float*)d_in[6], (const float*)d_in[8]};
    const float* b[4] = {(const float*)d_in[3], (const float*)d_in[5],
                         (const float*)d_in[7], (const float*)d_in[9]};
    float* out = (float*)d_out;

    char* ws = (char*)d_ws;
    size_t off = 0;
    auto alloc = [&](size_t bytes) -> void* {
        void* p = ws + off;
        off = (off + bytes + 255) & ~(size_t)255;
        return p;
    };
    __half* G16   = (__half*)alloc((size_t)N_NODES * DIM * sizeof(__half));   // 12.8 MB
    __half* ACT16 = (__half*)alloc((size_t)N_NODES * DIM * sizeof(__half));   // 12.8 MB
    __half* WT16  = (__half*)alloc((size_t)4 * DIM * DIM * sizeof(__half));   // 32 KB
    int*   csr    = (int*)alloc((size_t)N_EDGES * sizeof(int));               // 6.4 MB
    int*   bdata  = (int*)alloc((size_t)NBUCK * BCAP * sizeof(int));          // 12.8 MB
    int*   gcur   = (int*)alloc((size_t)NBUCK * 16 * sizeof(int));            // 50 KB
    int*   offsets= (int*)alloc((size_t)(N_NODES + 1) * sizeof(int));
    float* dinv   = (float*)alloc((size_t)N_NODES * sizeof(float));

    hipMemsetAsync(gcur, 0, (size_t)NBUCK * 16 * sizeof(int), stream);
    prep_weights<<<4, 256, 0, stream>>>(W[0], W[1], W[2], W[3], WT16);

    bucket_scatter<<<BLOCKS1, THREADS1, 0, stream>>>(src, dst, gcur, bdata);
    bucket_build<<<NBUCK, 256, 0, stream>>>(bdata, gcur, offsets, dinv, csr);

    const int MM_GRID = (N_NODES + 63) / 64;          // 1563

    mm_kernel<float><<<MM_GRID, 256, 0, stream>>>(x, WT16, dinv, G16);
    agg_kernel<false><<<AGG_BLOCKS, 256, 0, stream>>>(G16, csr, offsets, dinv, b[0], ACT16);
    mm_kernel<__half><<<MM_GRID, 256, 0, stream>>>(ACT16, WT16 + DIM * DIM, dinv, G16);
    agg_kernel<false><<<AGG_BLOCKS, 256, 0, stream>>>(G16, csr, offsets, dinv, b[1], ACT16);
    mm_kernel<__half><<<MM_GRID, 256, 0, stream>>>(ACT16, WT16 + 2 * DIM * DIM, dinv, G16);
    agg_kernel<false><<<AGG_BLOCKS, 256, 0, stream>>>(G16, csr, offsets, dinv, b[2], ACT16);
    mm_kernel<__half><<<MM_GRID, 256, 0, stream>>>(ACT16, WT16 + 3 * DIM * DIM, dinv, G16);
    agg_kernel<true><<<AGG_BLOCKS, 256, 0, stream>>>(G16, csr, offsets, dinv, b[3], out);
}